// Round 9
// baseline (300.310 us; speedup 1.0000x reference)
//
#include <hip/hip_runtime.h>
#include <math.h>

#define NB    4
#define NSEQ  2048
#define DMODEL 512
#define NH    8
#define HDIM  64
#define STR   72   // attn LDS tile row stride (bf16 units): 144B rows, 16B-aligned
#define LOG2E 1.44269504088896f

typedef __attribute__((ext_vector_type(8))) short short8;
typedef __attribute__((ext_vector_type(4))) float f32x4;
#define MFMA16 __builtin_amdgcn_mfma_f32_16x16x32_bf16
#define EXP2F __builtin_amdgcn_exp2f

__device__ __forceinline__ unsigned short f2bf(float f) {
    union { float f; unsigned int u; } v; v.f = f;
    unsigned int u = v.u;
    unsigned int r = (u + 0x7FFFu + ((u >> 16) & 1u)) >> 16;   // RNE
    return (unsigned short)r;
}
__device__ __forceinline__ float bf2f(unsigned short h) {
    union { unsigned int u; float f; } v; v.u = ((unsigned int)h) << 16;
    return v.f;
}
// AND a P-fragment (8 bf16, keys j=0..7) with 8 adjacency bits
__device__ __forceinline__ short8 andmask8(short8 p, unsigned bits) {
    union { short8 s; uint4 u; } x; x.s = p;
    x.u.x &= ((bits &   1u) ? 0xFFFFu : 0u) | ((bits &   2u) ? 0xFFFF0000u : 0u);
    x.u.y &= ((bits &   4u) ? 0xFFFFu : 0u) | ((bits &   8u) ? 0xFFFF0000u : 0u);
    x.u.z &= ((bits &  16u) ? 0xFFFFu : 0u) | ((bits &  32u) ? 0xFFFF0000u : 0u);
    x.u.w &= ((bits &  64u) ? 0xFFFFu : 0u) | ((bits & 128u) ? 0xFFFF0000u : 0u);
    return x.s;
}
__device__ __forceinline__ void async16(void* lds, const void* g) {
    __builtin_amdgcn_global_load_lds(
        (const __attribute__((address_space(1))) unsigned int*)g,
        (__attribute__((address_space(3))) unsigned int*)lds, 16, 0, 0);
}

// ---------------------------------------------------------------------------
// Fused prep: [0,16384) mask bitify; [16384,20480) split x; [20480,21504) W^T split.
// ---------------------------------------------------------------------------
__global__ __launch_bounds__(256) void prep_kernel(
    const float* __restrict__ adj, const float* __restrict__ x,
    const float* __restrict__ Wq, const float* __restrict__ Wk,
    const float* __restrict__ Wv, const float* __restrict__ Wo,
    unsigned long long* __restrict__ Mb,
    unsigned short* __restrict__ xhi, unsigned short* __restrict__ xlo,
    unsigned short* __restrict__ Wthi, unsigned short* __restrict__ Wtlo)
{
    __shared__ float tile[32][33];
    const int bx = blockIdx.x;
    if (bx < 16384) {
        // Mb[kt*2048+q] bit i = adj[q][kt*64+i] > 0.5
        const int w    = bx * 4 + (threadIdx.x >> 6);
        const int lane = threadIdx.x & 63;
        const int q  = w >> 5;
        const int kt = w & 31;
        float a = adj[(size_t)q * NSEQ + kt * 64 + lane];
        unsigned long long m = __ballot(a > 0.5f);
        if (lane == 0) Mb[(size_t)kt * NSEQ + q] = m;
    } else if (bx < 16384 + 4096) {
        int gid = (bx - 16384) * 256 + threadIdx.x;
        float4 a = ((const float4*)x)[gid];
        float f[4] = {a.x, a.y, a.z, a.w};
        ushort4 h4, l4;
        unsigned short hs[4], ls[4];
        #pragma unroll
        for (int j = 0; j < 4; ++j) {
            hs[j] = f2bf(f[j]);
            ls[j] = f2bf(f[j] - bf2f(hs[j]));
        }
        h4.x = hs[0]; h4.y = hs[1]; h4.z = hs[2]; h4.w = hs[3];
        l4.x = ls[0]; l4.y = ls[1]; l4.z = ls[2]; l4.w = ls[3];
        ((ushort4*)xhi)[gid] = h4;
        ((ushort4*)xlo)[gid] = l4;
    } else {
        const int r = bx - 20480;            // 0..1023 = (nb<<6)|(kb<<2)|m
        const int m  = r & 3;
        const int kb = (r >> 2) & 15;
        const int nb = r >> 6;
        const float* W = (m == 0) ? Wq : (m == 1) ? Wk : (m == 2) ? Wv : Wo;
        const int k0 = kb * 32, n0 = nb * 32;
        const int tx = threadIdx.x & 31, ty = threadIdx.x >> 5;
        #pragma unroll
        for (int i = 0; i < 4; ++i)
            tile[ty * 4 + i][tx] = W[(size_t)(k0 + ty * 4 + i) * DMODEL + n0 + tx];
        __syncthreads();
        const size_t base = ((size_t)m * DMODEL) * DMODEL;
        #pragma unroll
        for (int i = 0; i < 4; ++i) {
            float f = tile[tx][ty * 4 + i];
            unsigned short hi = f2bf(f);
            unsigned short lo = f2bf(f - bf2f(hi));
            size_t idx = base + (size_t)(n0 + ty * 4 + i) * DMODEL + k0 + tx;
            Wthi[idx] = hi;
            Wtlo[idx] = lo;
        }
    }
}

// ---------------------------------------------------------------------------
// Shared MFMA GEMM K-loop (hi/lo 3-term), 128x128 tile, BK=32, XOR-swizzled LDS.
// ---------------------------------------------------------------------------
__device__ __forceinline__ void gemm_k_loop(
    const unsigned short* __restrict__ Ah, const unsigned short* __restrict__ Al,
    const unsigned short* __restrict__ Bh, const unsigned short* __restrict__ Bl,
    char* smem, f32x4 acc[4][4])
{
    const int t    = threadIdx.x;
    const int lane = t & 63;
    const int wid  = t >> 6;
    const int quad = lane >> 4, l16 = lane & 15;
    const int wm   = wid >> 1,  wn  = wid & 1;

    unsigned short* As_h = (unsigned short*)(smem);
    unsigned short* As_l = (unsigned short*)(smem + 8192);
    unsigned short* Bs_h = (unsigned short*)(smem + 16384);
    unsigned short* Bs_l = (unsigned short*)(smem + 24576);

    const int ci0 = t, ci1 = 256 + t;
    const int r0 = ci0 >> 2, r1 = ci1 >> 2;
    const int c0 = (ci0 & 3) ^ ((r0 >> 1) & 3);
    const int c1 = (ci1 & 3) ^ ((r1 >> 1) & 3);
    const char* gAh = (const char*)Ah;  const char* gAl = (const char*)Al;
    const char* gBh = (const char*)Bh;  const char* gBl = (const char*)Bl;
    const int ca = quad ^ ((l16 >> 1) & 3);

    for (int k0 = 0; k0 < DMODEL; k0 += 32) {
        const int kb = k0 * 2;
        async16(As_h + ci0 * 8, gAh + r0 * 1024 + kb + c0 * 16);
        async16(As_h + ci1 * 8, gAh + r1 * 1024 + kb + c1 * 16);
        async16(As_l + ci0 * 8, gAl + r0 * 1024 + kb + c0 * 16);
        async16(As_l + ci1 * 8, gAl + r1 * 1024 + kb + c1 * 16);
        async16(Bs_h + ci0 * 8, gBh + r0 * 1024 + kb + c0 * 16);
        async16(Bs_h + ci1 * 8, gBh + r1 * 1024 + kb + c1 * 16);
        async16(Bs_l + ci0 * 8, gBl + r0 * 1024 + kb + c0 * 16);
        async16(Bs_l + ci1 * 8, gBl + r1 * 1024 + kb + c1 * 16);
        __syncthreads();

        short8 ah[4], al[4], bh[4], bl[4];
        #pragma unroll
        for (int i = 0; i < 4; ++i) {
            const int Ra = wm * 64 + i * 16 + l16;
            ah[i] = *(const short8*)(As_h + Ra * 32 + ca * 8);
            al[i] = *(const short8*)(As_l + Ra * 32 + ca * 8);
            const int Rb = wn * 64 + i * 16 + l16;
            bh[i] = *(const short8*)(Bs_h + Rb * 32 + ca * 8);
            bl[i] = *(const short8*)(Bs_l + Rb * 32 + ca * 8);
        }
        #pragma unroll
        for (int mi = 0; mi < 4; ++mi)
            #pragma unroll
            for (int ni = 0; ni < 4; ++ni) {
                acc[mi][ni] = MFMA16(ah[mi], bh[ni], acc[mi][ni], 0, 0, 0);
                acc[mi][ni] = MFMA16(al[mi], bh[ni], acc[mi][ni], 0, 0, 0);
                acc[mi][ni] = MFMA16(ah[mi], bl[ni], acc[mi][ni], 0, 0, 0);
            }
        __syncthreads();
    }
}

// ---------------------------------------------------------------------------
// QKV projection (MFMA). Q: *(0.125*log2e) hi/lo; K: hi only; V: bf16 transposed.
// Q/K epilogue: per-wave LDS transpose -> fully coalesced uint4 global stores.
// ---------------------------------------------------------------------------
__global__ __launch_bounds__(256, 2) void qkv_mfma_kernel(
    const unsigned short* __restrict__ xhi, const unsigned short* __restrict__ xlo,
    const unsigned short* __restrict__ Wthi, const unsigned short* __restrict__ Wtlo,
    const float* __restrict__ bq, const float* __restrict__ bk, const float* __restrict__ bv,
    unsigned short* __restrict__ Qhi, unsigned short* __restrict__ Qlo,
    unsigned short* __restrict__ Khi,
    unsigned short* __restrict__ Vt)
{
    __shared__ __align__(16) char smem[33280];
    const int t    = threadIdx.x;
    const int lane = t & 63;
    const int wid  = t >> 6;
    const int quad = lane >> 4, l16 = lane & 15;
    const int wm   = wid >> 1,  wn  = wid & 1;

    const int row0 = blockIdx.x * 128;
    const int yb   = blockIdx.y;
    const int mtx  = yb >> 2;
    const int col0 = (yb & 3) * 128;

    f32x4 acc[4][4];
    #pragma unroll
    for (int i = 0; i < 4; ++i)
        #pragma unroll
        for (int j = 0; j < 4; ++j) acc[i][j] = (f32x4){0.f, 0.f, 0.f, 0.f};

    const size_t wslot = (size_t)mtx * DMODEL * DMODEL;
    gemm_k_loop(xhi + (size_t)row0 * DMODEL, xlo + (size_t)row0 * DMODEL,
                Wthi + wslot + (size_t)col0 * DMODEL, Wtlo + wslot + (size_t)col0 * DMODEL,
                smem, acc);

    const float* bias = (mtx == 0) ? bq : (mtx == 1) ? bk : bv;
    float bcol[4];
    #pragma unroll
    for (int ni = 0; ni < 4; ++ni) bcol[ni] = bias[col0 + wn * 64 + ni * 16 + l16];
    const int h = (col0 + wn * 64) >> 6;

    if (mtx < 2) {
        // Q: scale by 0.125*log2e so attention can use exp2 directly.
        const float scale = (mtx == 0) ? (0.125f * LOG2E) : 1.0f;
        unsigned short* hig = (mtx == 0) ? Qhi : Khi;
        float* wtile = (float*)smem + (size_t)wid * (32 * 65);
        #pragma unroll
        for (int p = 0; p < 2; ++p) {
            // write 32 rows (fp32, scaled+biased) to per-wave LDS tile
            #pragma unroll
            for (int m2 = 0; m2 < 2; ++m2) {
                const int mi = p * 2 + m2;
                #pragma unroll
                for (int ni = 0; ni < 4; ++ni)
                    #pragma unroll
                    for (int reg = 0; reg < 4; ++reg)
                        wtile[(m2 * 16 + quad * 4 + reg) * 65 + ni * 16 + l16] =
                            (acc[mi][ni][reg] + bcol[ni]) * scale;
            }
            // wave-ordered readback: lane owns half a row, coalesced uint4 stores
            const int rr = lane & 31, hh = lane >> 5;
            float f[32];
            #pragma unroll
            for (int jb = 0; jb < 8; ++jb)
                *(float4*)&f[jb * 4] = *(const float4*)&wtile[rr * 65 + hh * 32 + jb * 4];
            const int r  = row0 + wm * 64 + p * 32 + rr;
            const int bb = r >> 11, n = r & 2047;
            const size_t rowbase = ((size_t)(bb * NH + h) * NSEQ + n) * HDIM + hh * 32;
            unsigned hiw[16], low[16];
            #pragma unroll
            for (int j = 0; j < 16; ++j) {
                unsigned short h0 = f2bf(f[2 * j]), h1 = f2bf(f[2 * j + 1]);
                hiw[j] = (unsigned)h0 | ((unsigned)h1 << 16);
                if (mtx == 0) {
                    unsigned short l0 = f2bf(f[2 * j] - bf2f(h0));
                    unsigned short l1 = f2bf(f[2 * j + 1] - bf2f(h1));
                    low[j] = (unsigned)l0 | ((unsigned)l1 << 16);
                }
            }
            #pragma unroll
            for (int jb = 0; jb < 4; ++jb)
                *(uint4*)(hig + rowbase + jb * 8) = *(uint4*)&hiw[jb * 4];
            if (mtx == 0) {
                #pragma unroll
                for (int jb = 0; jb < 4; ++jb)
                    *(uint4*)(Qlo + rowbase + jb * 8) = *(uint4*)&low[jb * 4];
            }
        }
    } else {
        // V: bias + bf16, transpose 64x64 per wave through LDS (stride 65)
        unsigned short* vt = (unsigned short*)smem + (size_t)wid * 64 * 65;
        #pragma unroll
        for (int mi = 0; mi < 4; ++mi)
            #pragma unroll
            for (int ni = 0; ni < 4; ++ni)
                #pragma unroll
                for (int reg = 0; reg < 4; ++reg)
                    vt[(mi * 16 + quad * 4 + reg) * 65 + ni * 16 + l16] =
                        f2bf(acc[mi][ni][reg] + bcol[ni]);
        const int b   = row0 >> 11;
        const int n0g = (row0 & 2047) + wm * 64;
        const int bh  = b * NH + h;
        unsigned short* gdst = Vt + ((size_t)bh * HDIM + lane) * NSEQ + n0g;
        #pragma unroll
        for (int nb = 0; nb < 8; ++nb) {
            unsigned short v[8];
            #pragma unroll
            for (int j = 0; j < 8; ++j) v[j] = vt[(nb * 8 + j) * 65 + lane];
            uint4 u;
            u.x = (unsigned)v[0] | ((unsigned)v[1] << 16);
            u.y = (unsigned)v[2] | ((unsigned)v[3] << 16);
            u.z = (unsigned)v[4] | ((unsigned)v[5] << 16);
            u.w = (unsigned)v[6] | ((unsigned)v[7] << 16);
            *(uint4*)(gdst + nb * 8) = u;
        }
    }
}

// ---------------------------------------------------------------------------
// Output projection (MFMA): ctx(hi/lo) @ Wo^T + bo -> out fp32 [B,N,D]
// ---------------------------------------------------------------------------
__global__ __launch_bounds__(256, 2) void out_mfma_kernel(
    const unsigned short* __restrict__ chi, const unsigned short* __restrict__ clo,
    const unsigned short* __restrict__ Wthi, const unsigned short* __restrict__ Wtlo,
    const float* __restrict__ bo, float* __restrict__ out)
{
    __shared__ __align__(16) char smem[32768];
    const int t    = threadIdx.x;
    const int lane = t & 63;
    const int wid  = t >> 6;
    const int quad = lane >> 4, l16 = lane & 15;
    const int wm   = wid >> 1,  wn  = wid & 1;

    const int row0 = blockIdx.x * 128;
    const int col0 = blockIdx.y * 128;

    f32x4 acc[4][4];
    #pragma unroll
    for (int i = 0; i < 4; ++i)
        #pragma unroll
        for (int j = 0; j < 4; ++j) acc[i][j] = (f32x4){0.f, 0.f, 0.f, 0.f};

    const size_t wslot = (size_t)3 * DMODEL * DMODEL;   // Wo
    gemm_k_loop(chi + (size_t)row0 * DMODEL, clo + (size_t)row0 * DMODEL,
                Wthi + wslot + (size_t)col0 * DMODEL, Wtlo + wslot + (size_t)col0 * DMODEL,
                smem, acc);

    float bcol[4];
    #pragma unroll
    for (int ni = 0; ni < 4; ++ni) bcol[ni] = bo[col0 + wn * 64 + ni * 16 + l16];
    #pragma unroll
    for (int mi = 0; mi < 4; ++mi)
        #pragma unroll
        for (int reg = 0; reg < 4; ++reg) {
            const int r = row0 + wm * 64 + mi * 16 + quad * 4 + reg;
            float* orow = out + (size_t)r * DMODEL + col0 + wn * 64 + l16;
            #pragma unroll
            for (int ni = 0; ni < 4; ++ni)
                orow[ni * 16] = acc[mi][ni][reg] + bcol[ni];
        }
}

// ---------------------------------------------------------------------------
// MFMA flash attention (r5 structure = best measured, + 2 changes):
//  * p = exp2(s) directly via v_exp_f32 (Q pre-scaled by 0.125*log2e)
//  * V fragments read straight from global (vmem pipe) instead of LDS —
//    issued right after the barrier, consumed after S-MFMA+exp (~400cyc later);
//    at 16 waves/CU the latency is covered (r6 failed at 8 waves/CU).
// Block = 8 waves x 16 q-rows = 128 q, 512 threads, 512 blocks (2/CU).
// K tile staged in LDS; mask via 64-bit bitmask AND; l-sum via ones B-frag.
// ---------------------------------------------------------------------------
__global__ __launch_bounds__(512) void attn_kernel(
    const unsigned short* __restrict__ Qhi, const unsigned short* __restrict__ Qlo,
    const unsigned short* __restrict__ Khi,
    const unsigned short* __restrict__ Vt,
    const unsigned long long* __restrict__ Mb,
    unsigned short* __restrict__ chi, unsigned short* __restrict__ clo)
{
    __shared__ __align__(16) unsigned short KS[64 * STR];      // 9.2 KB
    __shared__ __align__(16) unsigned short PS[8][16 * STR];   // 18.4 KB

    const int t    = threadIdx.x;
    const int wq   = t >> 6;        // wave 0..7
    const int lane = t & 63;
    const int quad = lane >> 4;
    const int l16  = lane & 15;
    const int q0   = blockIdx.x * 128;
    const int h    = blockIdx.y;
    const int b    = blockIdx.z;
    const int bh   = b * NH + h;

    // Q fragments (A-operand), scaled by 0.125*log2e at projection time
    short8 qh[2], ql[2];
    {
        const int qrow = q0 + wq * 16 + l16;
        const unsigned short* gq = Qhi + ((size_t)bh * NSEQ + qrow) * HDIM + quad * 8;
        const unsigned short* gl = Qlo + ((size_t)bh * NSEQ + qrow) * HDIM + quad * 8;
        qh[0] = *(const short8*)gq;  qh[1] = *(const short8*)(gq + 32);
        ql[0] = *(const short8*)gl;  ql[1] = *(const short8*)(gl + 32);
    }
    const unsigned long long* mrow = Mb + (q0 + wq * 16 + l16);

    short8 onesf;
    #pragma unroll
    for (int i = 0; i < 8; ++i) onesf[i] = (short)0x3F80;   // bf16 1.0

    f32x4 O[5];
    #pragma unroll
    for (int ng = 0; ng < 5; ++ng) O[ng] = (f32x4){0.f, 0.f, 0.f, 0.f};

    const unsigned short* gk = Khi + (size_t)bh * NSEQ * HDIM;
    const unsigned short* gv = Vt  + (size_t)bh * HDIM * NSEQ;
    unsigned short* ps = &PS[wq][0];

    const int sr = t >> 3;           // 0..63  (512 thr, 1 uint4 each)
    const int sc = (t & 7) * 8;      // 0..56

    for (int kt = 0; kt < NSEQ / 64; ++kt) {
        const int k0 = kt * 64;
        // ---- stage K tile only ----
        *(uint4*)&KS[sr * STR + sc] = *(const uint4*)(gk + (size_t)(k0 + sr) * HDIM + sc);
        __syncthreads();

        // ---- V fragments straight from global: issue early, consume late ----
        short8 vf[4][2];
        #pragma unroll
        for (int ng = 0; ng < 4; ++ng) {
            const unsigned short* vr = gv + (size_t)(ng * 16 + l16) * NSEQ + k0 + quad * 8;
            vf[ng][0] = *(const short8*)vr;
            vf[ng][1] = *(const short8*)(vr + 32);
        }
        const unsigned long long mw = mrow[(size_t)kt * NSEQ];

        // ---- S' = (Qhi+Qlo) K^T (log2-scaled) ; p = exp2(s') -> PS ----
        #pragma unroll
        for (int cg = 0; cg < 4; ++cg) {
            f32x4 s = (f32x4){0.f, 0.f, 0.f, 0.f};
            short8 kh0 = *(const short8*)&KS[(cg * 16 + l16) * STR + quad * 8];
            short8 kh1 = *(const short8*)&KS[(cg * 16 + l16) * STR + 32 + quad * 8];
            s = MFMA16(qh[0], kh0, s, 0, 0, 0);
            s = MFMA16(ql[0], kh0, s, 0, 0, 0);
            s = MFMA16(qh[1], kh1, s, 0, 0, 0);
            s = MFMA16(ql[1], kh1, s, 0, 0, 0);
            #pragma unroll
            for (int r4 = 0; r4 < 4; ++r4) {
                float p = EXP2F(s[r4]);
                ps[(quad * 4 + r4) * STR + cg * 16 + l16] =
                    (unsigned short)(__float_as_uint(p) >> 16);
            }
        }

        // ---- P in A-layout, apply bitmask ----
        short8 p0 = *(const short8*)&ps[l16 * STR + quad * 8];
        short8 p1 = *(const short8*)&ps[l16 * STR + 32 + quad * 8];
        p0 = andmask8(p0, ((unsigned)mw         >> (quad * 8)) & 0xFFu);
        p1 = andmask8(p1, ((unsigned)(mw >> 32) >> (quad * 8)) & 0xFFu);

        // ---- O += P @ V ; l += P @ ones ----
        #pragma unroll
        for (int ng = 0; ng < 4; ++ng) {
            O[ng] = MFMA16(p0, vf[ng][0], O[ng], 0, 0, 0);
            O[ng] = MFMA16(p1, vf[ng][1], O[ng], 0, 0, 0);
        }
        O[4] = MFMA16(p0, onesf, O[4], 0, 0, 0);
        O[4] = MFMA16(p1, onesf, O[4], 0, 0, 0);

        __syncthreads();   // protect KS before next staging
    }

    // ---- normalize by l (= O[4], same value in every column), write ctx ----
    #pragma unroll
    for (int r4 = 0; r4 < 4; ++r4) {
        const float inv = 1.0f / O[4][r4];
        const int qrow = q0 + wq * 16 + quad * 4 + r4;
        const size_t base = ((size_t)b * NSEQ + qrow) * DMODEL + h * HDIM + l16;
        #pragma unroll
        for (int ng = 0; ng < 4; ++ng) {
            float f = O[ng][r4] * inv;
            unsigned short hi = f2bf(f);
            unsigned short lo = f2bf(f - bf2f(hi));
            chi[base + ng * 16] = hi;
            clo[base + ng * 16] = lo;
        }
    }
}

// ---------------------------------------------------------------------------
extern "C" void kernel_launch(void* const* d_in, const int* in_sizes, int n_in,
                              void* d_out, int out_size, void* d_ws, size_t ws_size,
                              hipStream_t stream) {
    const float* x   = (const float*)d_in[0];
    const float* adj = (const float*)d_in[1];
    const float* Wq  = (const float*)d_in[2];
    const float* bq  = (const float*)d_in[3];
    const float* Wk  = (const float*)d_in[4];
    const float* bk  = (const float*)d_in[5];
    const float* Wv  = (const float*)d_in[6];
    const float* bv  = (const float*)d_in[7];
    const float* Wo  = (const float*)d_in[8];
    const float* bo  = (const float*)d_in[9];
    float* out = (float*)d_out;

    const size_t elems = (size_t)NB * NSEQ * DMODEL;   // 4,194,304
    unsigned short* Qhi  = (unsigned short*)d_ws;
    unsigned short* Qlo  = Qhi + elems;
    unsigned short* Khi  = Qlo + elems;
    unsigned short* Klo  = Khi + elems;                // unused (layout stability)
    unsigned short* Vt   = Klo + elems;
    unsigned long long* Mbits = (unsigned long long*)(Vt + elems);  // 512 KB slot
    unsigned short* xhi  = Vt + 2 * elems;             // after the mask slot
    unsigned short* xlo  = xhi + elems;
    unsigned short* Wthi = xlo + elems;                // 4 * 512*512
    unsigned short* Wtlo = Wthi + 4 * (size_t)DMODEL * DMODEL;
    // ctx aliases xhi/xlo (dead after qkv_mfma_kernel)
    unsigned short* chi = xhi;
    unsigned short* clo = xlo;

    prep_kernel<<<dim3(16384 + 4096 + 1024), dim3(256), 0, stream>>>(
        adj, x, Wq, Wk, Wv, Wo, Mbits, xhi, xlo, Wthi, Wtlo);
    qkv_mfma_kernel<<<dim3(64, 12), dim3(256), 0, stream>>>(
        xhi, xlo, Wthi, Wtlo, bq, bk, bv, Qhi, Qlo, Khi, Vt);
    attn_kernel<<<dim3(NSEQ / 128, NH, NB), dim3(512), 0, stream>>>(
        Qhi, Qlo, Khi, Vt, Mbits, chi, clo);
    out_mfma_kernel<<<dim3(64, 4), dim3(256), 0, stream>>>(
        chi, clo, Wthi, Wtlo, bo, out);
}

// Round 10
// 234.962 us; speedup vs baseline: 1.2781x; 1.2781x over previous
//
#include <hip/hip_runtime.h>
#include <math.h>

#define NB    4
#define NSEQ  2048
#define DMODEL 512
#define NH    8
#define HDIM  64
#define STR   72   // attn LDS tile row stride (bf16 units): 144B rows, 16B-aligned
#define LOG2E 1.44269504088896f

typedef __attribute__((ext_vector_type(8))) short short8;
typedef __attribute__((ext_vector_type(4))) float f32x4;
#define MFMA16 __builtin_amdgcn_mfma_f32_16x16x32_bf16
#define EXP2F __builtin_amdgcn_exp2f

__device__ __forceinline__ unsigned short f2bf(float f) {
    union { float f; unsigned int u; } v; v.f = f;
    unsigned int u = v.u;
    unsigned int r = (u + 0x7FFFu + ((u >> 16) & 1u)) >> 16;   // RNE
    return (unsigned short)r;
}
__device__ __forceinline__ float bf2f(unsigned short h) {
    union { unsigned int u; float f; } v; v.u = ((unsigned int)h) << 16;
    return v.f;
}
// AND a P-fragment (8 bf16, keys j=0..7) with 8 adjacency bits
__device__ __forceinline__ short8 andmask8(short8 p, unsigned bits) {
    union { short8 s; uint4 u; } x; x.s = p;
    x.u.x &= ((bits &   1u) ? 0xFFFFu : 0u) | ((bits &   2u) ? 0xFFFF0000u : 0u);
    x.u.y &= ((bits &   4u) ? 0xFFFFu : 0u) | ((bits &   8u) ? 0xFFFF0000u : 0u);
    x.u.z &= ((bits &  16u) ? 0xFFFFu : 0u) | ((bits &  32u) ? 0xFFFF0000u : 0u);
    x.u.w &= ((bits &  64u) ? 0xFFFFu : 0u) | ((bits & 128u) ? 0xFFFF0000u : 0u);
    return x.s;
}
__device__ __forceinline__ void async16(void* lds, const void* g) {
    __builtin_amdgcn_global_load_lds(
        (const __attribute__((address_space(1))) unsigned int*)g,
        (__attribute__((address_space(3))) unsigned int*)lds, 16, 0, 0);
}

// ---------------------------------------------------------------------------
// Mask precompute: Mb[kt*2048 + q] = 64-bit word, bit i = adj[q][kt*64+i] > 0.5
// ---------------------------------------------------------------------------
__global__ __launch_bounds__(256) void mask_kernel(const float* __restrict__ adj,
                                                   unsigned long long* __restrict__ Mb) {
    const int w    = blockIdx.x * 4 + (threadIdx.x >> 6);   // global wave id
    const int lane = threadIdx.x & 63;
    const int q  = w >> 5;          // 0..2047
    const int kt = w & 31;          // 0..31
    float a = adj[(size_t)q * NSEQ + kt * 64 + lane];
    unsigned long long m = __ballot(a > 0.5f);
    if (lane == 0) Mb[(size_t)kt * NSEQ + q] = m;
}

// ---------------------------------------------------------------------------
// Split x (fp32) -> xhi, xlo bf16
// ---------------------------------------------------------------------------
__global__ __launch_bounds__(256) void split_x_kernel(const float* __restrict__ x,
                                                      unsigned short* __restrict__ xhi,
                                                      unsigned short* __restrict__ xlo) {
    int gid = blockIdx.x * 256 + threadIdx.x;
    float4 a = ((const float4*)x)[gid];
    float f[4] = {a.x, a.y, a.z, a.w};
    ushort4 h4, l4;
    unsigned short hs[4], ls[4];
    #pragma unroll
    for (int j = 0; j < 4; ++j) {
        hs[j] = f2bf(f[j]);
        ls[j] = f2bf(f[j] - bf2f(hs[j]));
    }
    h4.x = hs[0]; h4.y = hs[1]; h4.z = hs[2]; h4.w = hs[3];
    l4.x = ls[0]; l4.y = ls[1]; l4.z = ls[2]; l4.w = ls[3];
    ((ushort4*)xhi)[gid] = h4;
    ((ushort4*)xlo)[gid] = l4;
}

// ---------------------------------------------------------------------------
// Transpose + split weights: W[k][n] fp32 -> Wt_hi/Wt_lo [mat][n][k] bf16.
// ---------------------------------------------------------------------------
__global__ __launch_bounds__(256) void split_wt_kernel(
    const float* __restrict__ Wq, const float* __restrict__ Wk,
    const float* __restrict__ Wv, const float* __restrict__ Wo,
    unsigned short* __restrict__ Wthi, unsigned short* __restrict__ Wtlo)
{
    __shared__ float tile[32][33];
    const int m = blockIdx.z;
    const float* W = (m == 0) ? Wq : (m == 1) ? Wk : (m == 2) ? Wv : Wo;
    const int k0 = blockIdx.x * 32, n0 = blockIdx.y * 32;
    const int tx = threadIdx.x & 31, ty = threadIdx.x >> 5;
    #pragma unroll
    for (int i = 0; i < 4; ++i)
        tile[ty * 4 + i][tx] = W[(size_t)(k0 + ty * 4 + i) * DMODEL + n0 + tx];
    __syncthreads();
    const size_t base = ((size_t)m * DMODEL) * DMODEL;
    #pragma unroll
    for (int i = 0; i < 4; ++i) {
        float f = tile[tx][ty * 4 + i];
        unsigned short hi = f2bf(f);
        unsigned short lo = f2bf(f - bf2f(hi));
        size_t idx = base + (size_t)(n0 + ty * 4 + i) * DMODEL + k0 + tx;
        Wthi[idx] = hi;
        Wtlo[idx] = lo;
    }
}

// ---------------------------------------------------------------------------
// Shared MFMA GEMM K-loop (hi/lo 3-term), 128x128 tile, BK=32, XOR-swizzled LDS.
// ---------------------------------------------------------------------------
__device__ __forceinline__ void gemm_k_loop(
    const unsigned short* __restrict__ Ah, const unsigned short* __restrict__ Al,
    const unsigned short* __restrict__ Bh, const unsigned short* __restrict__ Bl,
    char* smem, f32x4 acc[4][4])
{
    const int t    = threadIdx.x;
    const int lane = t & 63;
    const int wid  = t >> 6;
    const int quad = lane >> 4, l16 = lane & 15;
    const int wm   = wid >> 1,  wn  = wid & 1;

    unsigned short* As_h = (unsigned short*)(smem);
    unsigned short* As_l = (unsigned short*)(smem + 8192);
    unsigned short* Bs_h = (unsigned short*)(smem + 16384);
    unsigned short* Bs_l = (unsigned short*)(smem + 24576);

    const int ci0 = t, ci1 = 256 + t;
    const int r0 = ci0 >> 2, r1 = ci1 >> 2;
    const int c0 = (ci0 & 3) ^ ((r0 >> 1) & 3);
    const int c1 = (ci1 & 3) ^ ((r1 >> 1) & 3);
    const char* gAh = (const char*)Ah;  const char* gAl = (const char*)Al;
    const char* gBh = (const char*)Bh;  const char* gBl = (const char*)Bl;
    const int ca = quad ^ ((l16 >> 1) & 3);

    for (int k0 = 0; k0 < DMODEL; k0 += 32) {
        const int kb = k0 * 2;
        async16(As_h + ci0 * 8, gAh + r0 * 1024 + kb + c0 * 16);
        async16(As_h + ci1 * 8, gAh + r1 * 1024 + kb + c1 * 16);
        async16(As_l + ci0 * 8, gAl + r0 * 1024 + kb + c0 * 16);
        async16(As_l + ci1 * 8, gAl + r1 * 1024 + kb + c1 * 16);
        async16(Bs_h + ci0 * 8, gBh + r0 * 1024 + kb + c0 * 16);
        async16(Bs_h + ci1 * 8, gBh + r1 * 1024 + kb + c1 * 16);
        async16(Bs_l + ci0 * 8, gBl + r0 * 1024 + kb + c0 * 16);
        async16(Bs_l + ci1 * 8, gBl + r1 * 1024 + kb + c1 * 16);
        __syncthreads();

        short8 ah[4], al[4], bh[4], bl[4];
        #pragma unroll
        for (int i = 0; i < 4; ++i) {
            const int Ra = wm * 64 + i * 16 + l16;
            ah[i] = *(const short8*)(As_h + Ra * 32 + ca * 8);
            al[i] = *(const short8*)(As_l + Ra * 32 + ca * 8);
            const int Rb = wn * 64 + i * 16 + l16;
            bh[i] = *(const short8*)(Bs_h + Rb * 32 + ca * 8);
            bl[i] = *(const short8*)(Bs_l + Rb * 32 + ca * 8);
        }
        #pragma unroll
        for (int mi = 0; mi < 4; ++mi)
            #pragma unroll
            for (int ni = 0; ni < 4; ++ni) {
                acc[mi][ni] = MFMA16(ah[mi], bh[ni], acc[mi][ni], 0, 0, 0);
                acc[mi][ni] = MFMA16(al[mi], bh[ni], acc[mi][ni], 0, 0, 0);
                acc[mi][ni] = MFMA16(ah[mi], bl[ni], acc[mi][ni], 0, 0, 0);
            }
        __syncthreads();
    }
}

// ---------------------------------------------------------------------------
// QKV projection (MFMA). Q: *(0.125*log2e) hi/lo; K: hi only; V: bf16 transposed.
// ---------------------------------------------------------------------------
__global__ __launch_bounds__(256, 2) void qkv_mfma_kernel(
    const unsigned short* __restrict__ xhi, const unsigned short* __restrict__ xlo,
    const unsigned short* __restrict__ Wthi, const unsigned short* __restrict__ Wtlo,
    const float* __restrict__ bq, const float* __restrict__ bk, const float* __restrict__ bv,
    unsigned short* __restrict__ Qhi, unsigned short* __restrict__ Qlo,
    unsigned short* __restrict__ Khi,
    unsigned short* __restrict__ Vt)
{
    __shared__ __align__(16) char smem[33280];
    const int t    = threadIdx.x;
    const int lane = t & 63;
    const int wid  = t >> 6;
    const int quad = lane >> 4, l16 = lane & 15;
    const int wm   = wid >> 1,  wn  = wid & 1;

    const int row0 = blockIdx.x * 128;
    const int yb   = blockIdx.y;
    const int mtx  = yb >> 2;
    const int col0 = (yb & 3) * 128;

    f32x4 acc[4][4];
    #pragma unroll
    for (int i = 0; i < 4; ++i)
        #pragma unroll
        for (int j = 0; j < 4; ++j) acc[i][j] = (f32x4){0.f, 0.f, 0.f, 0.f};

    const size_t wslot = (size_t)mtx * DMODEL * DMODEL;
    gemm_k_loop(xhi + (size_t)row0 * DMODEL, xlo + (size_t)row0 * DMODEL,
                Wthi + wslot + (size_t)col0 * DMODEL, Wtlo + wslot + (size_t)col0 * DMODEL,
                smem, acc);

    const float* bias = (mtx == 0) ? bq : (mtx == 1) ? bk : bv;
    float bcol[4];
    #pragma unroll
    for (int ni = 0; ni < 4; ++ni) bcol[ni] = bias[col0 + wn * 64 + ni * 16 + l16];
    const int h = (col0 + wn * 64) >> 6;

    if (mtx < 2) {
        // Q scaled by 0.125*log2e so attention uses exp2 directly.
        const float scale = (mtx == 0) ? (0.125f * LOG2E) : 1.0f;
        unsigned short* hig = (mtx == 0) ? Qhi : Khi;
        #pragma unroll
        for (int mi = 0; mi < 4; ++mi) {
            #pragma unroll
            for (int reg = 0; reg < 4; ++reg) {
                const int r = row0 + wm * 64 + mi * 16 + quad * 4 + reg;
                const int b = r >> 11, n = r & 2047;
                const size_t rowbase = ((size_t)(b * NH + h) * NSEQ + n) * HDIM;
                #pragma unroll
                for (int ni = 0; ni < 4; ++ni) {
                    float f = (acc[mi][ni][reg] + bcol[ni]) * scale;
                    unsigned short hi = f2bf(f);
                    hig[rowbase + ni * 16 + l16] = hi;
                    if (mtx == 0)
                        Qlo[rowbase + ni * 16 + l16] = f2bf(f - bf2f(hi));
                }
            }
        }
    } else {
        // V: bias + bf16, transpose 64x64 per wave through LDS (stride 65)
        unsigned short* vt = (unsigned short*)smem + (size_t)wid * 64 * 65;
        #pragma unroll
        for (int mi = 0; mi < 4; ++mi)
            #pragma unroll
            for (int ni = 0; ni < 4; ++ni)
                #pragma unroll
                for (int reg = 0; reg < 4; ++reg)
                    vt[(mi * 16 + quad * 4 + reg) * 65 + ni * 16 + l16] =
                        f2bf(acc[mi][ni][reg] + bcol[ni]);
        const int b   = row0 >> 11;
        const int n0g = (row0 & 2047) + wm * 64;
        const int bh  = b * NH + h;
        unsigned short* gdst = Vt + ((size_t)bh * HDIM + lane) * NSEQ + n0g;
        #pragma unroll
        for (int nb = 0; nb < 8; ++nb) {
            unsigned short v[8];
            #pragma unroll
            for (int j = 0; j < 8; ++j) v[j] = vt[(nb * 8 + j) * 65 + lane];
            uint4 u;
            u.x = (unsigned)v[0] | ((unsigned)v[1] << 16);
            u.y = (unsigned)v[2] | ((unsigned)v[3] << 16);
            u.z = (unsigned)v[4] | ((unsigned)v[5] << 16);
            u.w = (unsigned)v[6] | ((unsigned)v[7] << 16);
            *(uint4*)(gdst + nb * 8) = u;
        }
    }
}

// ---------------------------------------------------------------------------
// Output projection (MFMA): ctx(hi/lo) @ Wo^T + bo -> out fp32 [B,N,D]
// ---------------------------------------------------------------------------
__global__ __launch_bounds__(256, 2) void out_mfma_kernel(
    const unsigned short* __restrict__ chi, const unsigned short* __restrict__ clo,
    const unsigned short* __restrict__ Wthi, const unsigned short* __restrict__ Wtlo,
    const float* __restrict__ bo, float* __restrict__ out)
{
    __shared__ __align__(16) char smem[32768];
    const int t    = threadIdx.x;
    const int lane = t & 63;
    const int wid  = t >> 6;
    const int quad = lane >> 4, l16 = lane & 15;
    const int wm   = wid >> 1,  wn  = wid & 1;

    const int row0 = blockIdx.x * 128;
    const int col0 = blockIdx.y * 128;

    f32x4 acc[4][4];
    #pragma unroll
    for (int i = 0; i < 4; ++i)
        #pragma unroll
        for (int j = 0; j < 4; ++j) acc[i][j] = (f32x4){0.f, 0.f, 0.f, 0.f};

    const size_t wslot = (size_t)3 * DMODEL * DMODEL;   // Wo
    gemm_k_loop(chi + (size_t)row0 * DMODEL, clo + (size_t)row0 * DMODEL,
                Wthi + wslot + (size_t)col0 * DMODEL, Wtlo + wslot + (size_t)col0 * DMODEL,
                smem, acc);

    float bcol[4];
    #pragma unroll
    for (int ni = 0; ni < 4; ++ni) bcol[ni] = bo[col0 + wn * 64 + ni * 16 + l16];
    #pragma unroll
    for (int mi = 0; mi < 4; ++mi)
        #pragma unroll
        for (int reg = 0; reg < 4; ++reg) {
            const int r = row0 + wm * 64 + mi * 16 + quad * 4 + reg;
            float* orow = out + (size_t)r * DMODEL + col0 + wn * 64 + l16;
            #pragma unroll
            for (int ni = 0; ni < 4; ++ni)
                orow[ni * 16] = acc[mi][ni][reg] + bcol[ni];
        }
}

// ---------------------------------------------------------------------------
// MFMA flash attention — r5 structure (best measured: 84 µs) + exp2.
// Block = 128 q-rows x (head,batch), 512 threads = 8 waves x 16 q-rows.
// K/V tiles staged in LDS once per block serve all 8 waves (coalesced rows —
// fragment-pattern global reads are lane-scattered and must NOT bypass LDS).
// Mask: 64-bit/row bitmask from global (per-lane-row => coalesced enough).
// l-sum: constant ones B-frag. p = exp2(s'): Q pre-scaled by 0.125*log2e.
// ---------------------------------------------------------------------------
__global__ __launch_bounds__(512) void attn_kernel(
    const unsigned short* __restrict__ Qhi, const unsigned short* __restrict__ Qlo,
    const unsigned short* __restrict__ Khi,
    const unsigned short* __restrict__ Vt,
    const unsigned long long* __restrict__ Mb,
    unsigned short* __restrict__ chi, unsigned short* __restrict__ clo)
{
    __shared__ __align__(16) unsigned short KS[64 * STR];
    __shared__ __align__(16) unsigned short VS[64 * STR];
    __shared__ __align__(16) unsigned short PS[8][16 * STR];

    const int t    = threadIdx.x;
    const int wq   = t >> 6;        // wave 0..7
    const int lane = t & 63;
    const int quad = lane >> 4;
    const int l16  = lane & 15;
    const int q0   = blockIdx.x * 128;
    const int h    = blockIdx.y;
    const int b    = blockIdx.z;
    const int bh   = b * NH + h;

    // Q fragments (A-operand), scaled by 0.125*log2e at projection time
    short8 qh[2], ql[2];
    {
        const int qrow = q0 + wq * 16 + l16;
        const unsigned short* gq = Qhi + ((size_t)bh * NSEQ + qrow) * HDIM + quad * 8;
        const unsigned short* gl = Qlo + ((size_t)bh * NSEQ + qrow) * HDIM + quad * 8;
        qh[0] = *(const short8*)gq;  qh[1] = *(const short8*)(gq + 32);
        ql[0] = *(const short8*)gl;  ql[1] = *(const short8*)(gl + 32);
    }
    // per-lane mask row (this lane's q-row in A-layout)
    const unsigned long long* mrow = Mb + (q0 + wq * 16 + l16);

    short8 onesf;
    #pragma unroll
    for (int i = 0; i < 8; ++i) onesf[i] = (short)0x3F80;   // bf16 1.0

    f32x4 O[5];
    #pragma unroll
    for (int ng = 0; ng < 5; ++ng) O[ng] = (f32x4){0.f, 0.f, 0.f, 0.f};

    const unsigned short* gkbase = Khi + (size_t)bh * NSEQ * HDIM;
    const unsigned short* gvbase = Vt  + (size_t)bh * HDIM * NSEQ;
    unsigned short* ps = &PS[wq][0];

    for (int kt = 0; kt < NSEQ / 64; ++kt) {
        const int k0 = kt * 64;
        // ---- stage K, V tiles: 512 threads x 1 uint4 each per tile ----
        {
            const int r  = t >> 3;           // 0..63
            const int c4 = (t & 7) * 8;      // 0..56
            *(uint4*)&KS[r * STR + c4] = *(const uint4*)(gkbase + (size_t)(k0 + r) * HDIM + c4);
            *(uint4*)&VS[r * STR + c4] = *(const uint4*)(gvbase + (size_t)r * NSEQ + k0 + c4);
        }
        __syncthreads();

        // mask word for this lane's q-row, this key tile
        const unsigned long long mw = mrow[(size_t)kt * NSEQ];

        // ---- S' = (Qhi+Qlo) K^T (log2-scaled) ; p = exp2(s') -> PS ----
        #pragma unroll
        for (int cg = 0; cg < 4; ++cg) {
            f32x4 s = (f32x4){0.f, 0.f, 0.f, 0.f};
            short8 kh0 = *(const short8*)&KS[(cg * 16 + l16) * STR + quad * 8];
            short8 kh1 = *(const short8*)&KS[(cg * 16 + l16) * STR + 32 + quad * 8];
            s = MFMA16(qh[0], kh0, s, 0, 0, 0);
            s = MFMA16(ql[0], kh0, s, 0, 0, 0);
            s = MFMA16(qh[1], kh1, s, 0, 0, 0);
            s = MFMA16(ql[1], kh1, s, 0, 0, 0);
            #pragma unroll
            for (int r4 = 0; r4 < 4; ++r4) {
                float p = EXP2F(s[r4]);
                ps[(quad * 4 + r4) * STR + cg * 16 + l16] =
                    (unsigned short)(__float_as_uint(p) >> 16);
            }
        }

        // ---- read P in A-layout, apply bitmask ----
        short8 p0 = *(const short8*)&ps[l16 * STR + quad * 8];
        short8 p1 = *(const short8*)&ps[l16 * STR + 32 + quad * 8];
        p0 = andmask8(p0, ((unsigned)mw         >> (quad * 8)) & 0xFFu);
        p1 = andmask8(p1, ((unsigned)(mw >> 32) >> (quad * 8)) & 0xFFu);

        // ---- O += P @ V ; l += P @ ones ----
        #pragma unroll
        for (int ng = 0; ng < 4; ++ng) {
            short8 v0 = *(const short8*)&VS[(ng * 16 + l16) * STR + quad * 8];
            short8 v1 = *(const short8*)&VS[(ng * 16 + l16) * STR + 32 + quad * 8];
            O[ng] = MFMA16(p0, v0, O[ng], 0, 0, 0);
            O[ng] = MFMA16(p1, v1, O[ng], 0, 0, 0);
        }
        O[4] = MFMA16(p0, onesf, O[4], 0, 0, 0);
        O[4] = MFMA16(p1, onesf, O[4], 0, 0, 0);

        __syncthreads();
    }

    // ---- normalize by l (= O[4], same value in every column) and write ctx ----
    #pragma unroll
    for (int r4 = 0; r4 < 4; ++r4) {
        const float inv = 1.0f / O[4][r4];
        const int qrow = q0 + wq * 16 + quad * 4 + r4;
        const size_t base = ((size_t)b * NSEQ + qrow) * DMODEL + h * HDIM + l16;
        #pragma unroll
        for (int ng = 0; ng < 4; ++ng) {
            float f = O[ng][r4] * inv;
            unsigned short hi = f2bf(f);
            unsigned short lo = f2bf(f - bf2f(hi));
            chi[base + ng * 16] = hi;
            clo[base + ng * 16] = lo;
        }
    }
}

// ---------------------------------------------------------------------------
extern "C" void kernel_launch(void* const* d_in, const int* in_sizes, int n_in,
                              void* d_out, int out_size, void* d_ws, size_t ws_size,
                              hipStream_t stream) {
    const float* x   = (const float*)d_in[0];
    const float* adj = (const float*)d_in[1];
    const float* Wq  = (const float*)d_in[2];
    const float* bq  = (const float*)d_in[3];
    const float* Wk  = (const float*)d_in[4];
    const float* bk  = (const float*)d_in[5];
    const float* Wv  = (const float*)d_in[6];
    const float* bv  = (const float*)d_in[7];
    const float* Wo  = (const float*)d_in[8];
    const float* bo  = (const float*)d_in[9];
    float* out = (float*)d_out;

    const size_t elems = (size_t)NB * NSEQ * DMODEL;   // 4,194,304
    unsigned short* Qhi  = (unsigned short*)d_ws;
    unsigned short* Qlo  = Qhi + elems;
    unsigned short* Khi  = Qlo + elems;
    unsigned short* Klo  = Khi + elems;                // unused (layout stability)
    unsigned short* Vt   = Klo + elems;
    unsigned long long* Mbits = (unsigned long long*)(Vt + elems);  // 512 KB slot
    unsigned short* xhi  = Vt + 2 * elems;             // after the mask slot
    unsigned short* xlo  = xhi + elems;
    unsigned short* Wthi = xlo + elems;                // 4 * 512*512
    unsigned short* Wtlo = Wthi + 4 * (size_t)DMODEL * DMODEL;
    // ctx aliases xhi/xlo (dead after qkv_mfma_kernel)
    unsigned short* chi = xhi;
    unsigned short* clo = xlo;

    mask_kernel   <<<dim3(16384), dim3(256), 0, stream>>>(adj, Mbits);
    split_x_kernel<<<dim3(4096), dim3(256), 0, stream>>>(x, xhi, xlo);
    split_wt_kernel<<<dim3(16, 16, 4), dim3(256), 0, stream>>>(Wq, Wk, Wv, Wo, Wthi, Wtlo);
    qkv_mfma_kernel<<<dim3(64, 12), dim3(256), 0, stream>>>(
        xhi, xlo, Wthi, Wtlo, bq, bk, bv, Qhi, Qlo, Khi, Vt);
    attn_kernel<<<dim3(NSEQ / 128, NH, NB), dim3(512), 0, stream>>>(
        Qhi, Qlo, Khi, Vt, Mbits, chi, clo);
    out_mfma_kernel<<<dim3(64, 4), dim3(256), 0, stream>>>(
        chi, clo, Wthi, Wtlo, bo, out);
}

// Round 11
// 220.983 us; speedup vs baseline: 1.3590x; 1.0633x over previous
//
#include <hip/hip_runtime.h>
#include <math.h>

#define NB    4
#define NSEQ  2048
#define DMODEL 512
#define NH    8
#define HDIM  64
#define STR   72   // attn LDS tile row stride (bf16 units): 144B rows, 16B-aligned
#define LOG2E 1.44269504088896f

typedef __attribute__((ext_vector_type(8))) short short8;
typedef __attribute__((ext_vector_type(4))) float f32x4;
typedef __attribute__((ext_vector_type(16))) float f32x16;
#define MFMA16 __builtin_amdgcn_mfma_f32_16x16x32_bf16
#define MFMA32 __builtin_amdgcn_mfma_f32_32x32x16_bf16
#define EXP2F __builtin_amdgcn_exp2f

__device__ __forceinline__ unsigned short f2bf(float f) {
    union { float f; unsigned int u; } v; v.f = f;
    unsigned int u = v.u;
    unsigned int r = (u + 0x7FFFu + ((u >> 16) & 1u)) >> 16;   // RNE
    return (unsigned short)r;
}
__device__ __forceinline__ float bf2f(unsigned short h) {
    union { unsigned int u; float f; } v; v.u = ((unsigned int)h) << 16;
    return v.f;
}
// AND a P-fragment (8 bf16, keys j=0..7) with 8 adjacency bits
__device__ __forceinline__ short8 andmask8(short8 p, unsigned bits) {
    union { short8 s; uint4 u; } x; x.s = p;
    x.u.x &= ((bits &   1u) ? 0xFFFFu : 0u) | ((bits &   2u) ? 0xFFFF0000u : 0u);
    x.u.y &= ((bits &   4u) ? 0xFFFFu : 0u) | ((bits &   8u) ? 0xFFFF0000u : 0u);
    x.u.z &= ((bits &  16u) ? 0xFFFFu : 0u) | ((bits &  32u) ? 0xFFFF0000u : 0u);
    x.u.w &= ((bits &  64u) ? 0xFFFFu : 0u) | ((bits & 128u) ? 0xFFFF0000u : 0u);
    return x.s;
}
__device__ __forceinline__ void async16(void* lds, const void* g) {
    __builtin_amdgcn_global_load_lds(
        (const __attribute__((address_space(1))) unsigned int*)g,
        (__attribute__((address_space(3))) unsigned int*)lds, 16, 0, 0);
}

// ---------------------------------------------------------------------------
// Mask precompute: Mb[kt*2048 + q] = 64-bit word, bit i = adj[q][kt*64+i] > 0.5
// ---------------------------------------------------------------------------
__global__ __launch_bounds__(256) void mask_kernel(const float* __restrict__ adj,
                                                   unsigned long long* __restrict__ Mb) {
    const int w    = blockIdx.x * 4 + (threadIdx.x >> 6);
    const int lane = threadIdx.x & 63;
    const int q  = w >> 5;
    const int kt = w & 31;
    float a = adj[(size_t)q * NSEQ + kt * 64 + lane];
    unsigned long long m = __ballot(a > 0.5f);
    if (lane == 0) Mb[(size_t)kt * NSEQ + q] = m;
}

// ---------------------------------------------------------------------------
// Split x (fp32) -> xhi, xlo bf16
// ---------------------------------------------------------------------------
__global__ __launch_bounds__(256) void split_x_kernel(const float* __restrict__ x,
                                                      unsigned short* __restrict__ xhi,
                                                      unsigned short* __restrict__ xlo) {
    int gid = blockIdx.x * 256 + threadIdx.x;
    float4 a = ((const float4*)x)[gid];
    float f[4] = {a.x, a.y, a.z, a.w};
    ushort4 h4, l4;
    unsigned short hs[4], ls[4];
    #pragma unroll
    for (int j = 0; j < 4; ++j) {
        hs[j] = f2bf(f[j]);
        ls[j] = f2bf(f[j] - bf2f(hs[j]));
    }
    h4.x = hs[0]; h4.y = hs[1]; h4.z = hs[2]; h4.w = hs[3];
    l4.x = ls[0]; l4.y = ls[1]; l4.z = ls[2]; l4.w = ls[3];
    ((ushort4*)xhi)[gid] = h4;
    ((ushort4*)xlo)[gid] = l4;
}

// ---------------------------------------------------------------------------
// Transpose weights: W[k][n] fp32 -> Wt_hi [mat][n][k] bf16 (hi only, 2-term).
// ---------------------------------------------------------------------------
__global__ __launch_bounds__(256) void split_wt_kernel(
    const float* __restrict__ Wq, const float* __restrict__ Wk,
    const float* __restrict__ Wv, const float* __restrict__ Wo,
    unsigned short* __restrict__ Wthi)
{
    __shared__ float tile[32][33];
    const int m = blockIdx.z;
    const float* W = (m == 0) ? Wq : (m == 1) ? Wk : (m == 2) ? Wv : Wo;
    const int k0 = blockIdx.x * 32, n0 = blockIdx.y * 32;
    const int tx = threadIdx.x & 31, ty = threadIdx.x >> 5;
    #pragma unroll
    for (int i = 0; i < 4; ++i)
        tile[ty * 4 + i][tx] = W[(size_t)(k0 + ty * 4 + i) * DMODEL + n0 + tx];
    __syncthreads();
    const size_t base = ((size_t)m * DMODEL) * DMODEL;
    #pragma unroll
    for (int i = 0; i < 4; ++i) {
        float f = tile[tx][ty * 4 + i];
        size_t idx = base + (size_t)(n0 + ty * 4 + i) * DMODEL + k0 + tx;
        Wthi[idx] = f2bf(f);
    }
}

// ---------------------------------------------------------------------------
// Shared MFMA GEMM K-loop, 2-term (A hi+lo, B hi): 128x128 tile, BK=32,
// XOR-swizzled LDS, global_load_lds staging.
// ---------------------------------------------------------------------------
__device__ __forceinline__ void gemm_k_loop(
    const unsigned short* __restrict__ Ah, const unsigned short* __restrict__ Al,
    const unsigned short* __restrict__ Bh,
    char* smem, f32x4 acc[4][4])
{
    const int t    = threadIdx.x;
    const int lane = t & 63;
    const int wid  = t >> 6;
    const int quad = lane >> 4, l16 = lane & 15;
    const int wm   = wid >> 1,  wn  = wid & 1;

    unsigned short* As_h = (unsigned short*)(smem);
    unsigned short* As_l = (unsigned short*)(smem + 8192);
    unsigned short* Bs_h = (unsigned short*)(smem + 16384);

    const int ci0 = t, ci1 = 256 + t;
    const int r0 = ci0 >> 2, r1 = ci1 >> 2;
    const int c0 = (ci0 & 3) ^ ((r0 >> 1) & 3);
    const int c1 = (ci1 & 3) ^ ((r1 >> 1) & 3);
    const char* gAh = (const char*)Ah;  const char* gAl = (const char*)Al;
    const char* gBh = (const char*)Bh;
    const int ca = quad ^ ((l16 >> 1) & 3);

    for (int k0 = 0; k0 < DMODEL; k0 += 32) {
        const int kb = k0 * 2;
        async16(As_h + ci0 * 8, gAh + r0 * 1024 + kb + c0 * 16);
        async16(As_h + ci1 * 8, gAh + r1 * 1024 + kb + c1 * 16);
        async16(As_l + ci0 * 8, gAl + r0 * 1024 + kb + c0 * 16);
        async16(As_l + ci1 * 8, gAl + r1 * 1024 + kb + c1 * 16);
        async16(Bs_h + ci0 * 8, gBh + r0 * 1024 + kb + c0 * 16);
        async16(Bs_h + ci1 * 8, gBh + r1 * 1024 + kb + c1 * 16);
        __syncthreads();

        short8 ah[4], al[4], bh[4];
        #pragma unroll
        for (int i = 0; i < 4; ++i) {
            const int Ra = wm * 64 + i * 16 + l16;
            ah[i] = *(const short8*)(As_h + Ra * 32 + ca * 8);
            al[i] = *(const short8*)(As_l + Ra * 32 + ca * 8);
            const int Rb = wn * 64 + i * 16 + l16;
            bh[i] = *(const short8*)(Bs_h + Rb * 32 + ca * 8);
        }
        #pragma unroll
        for (int mi = 0; mi < 4; ++mi)
            #pragma unroll
            for (int ni = 0; ni < 4; ++ni) {
                acc[mi][ni] = MFMA16(ah[mi], bh[ni], acc[mi][ni], 0, 0, 0);
                acc[mi][ni] = MFMA16(al[mi], bh[ni], acc[mi][ni], 0, 0, 0);
            }
        __syncthreads();
    }
}

// ---------------------------------------------------------------------------
// QKV projection (MFMA). Q: *(0.125*log2e) hi/lo; K: hi only; V: bf16 transposed.
// ---------------------------------------------------------------------------
__global__ __launch_bounds__(256, 2) void qkv_mfma_kernel(
    const unsigned short* __restrict__ xhi, const unsigned short* __restrict__ xlo,
    const unsigned short* __restrict__ Wthi,
    const float* __restrict__ bq, const float* __restrict__ bk, const float* __restrict__ bv,
    unsigned short* __restrict__ Qhi, unsigned short* __restrict__ Qlo,
    unsigned short* __restrict__ Khi,
    unsigned short* __restrict__ Vt)
{
    __shared__ __align__(16) char smem[33280];
    const int t    = threadIdx.x;
    const int lane = t & 63;
    const int wid  = t >> 6;
    const int quad = lane >> 4, l16 = lane & 15;
    const int wm   = wid >> 1,  wn  = wid & 1;

    const int row0 = blockIdx.x * 128;
    const int yb   = blockIdx.y;
    const int mtx  = yb >> 2;
    const int col0 = (yb & 3) * 128;

    f32x4 acc[4][4];
    #pragma unroll
    for (int i = 0; i < 4; ++i)
        #pragma unroll
        for (int j = 0; j < 4; ++j) acc[i][j] = (f32x4){0.f, 0.f, 0.f, 0.f};

    const size_t wslot = (size_t)mtx * DMODEL * DMODEL;
    gemm_k_loop(xhi + (size_t)row0 * DMODEL, xlo + (size_t)row0 * DMODEL,
                Wthi + wslot + (size_t)col0 * DMODEL, smem, acc);

    const float* bias = (mtx == 0) ? bq : (mtx == 1) ? bk : bv;
    float bcol[4];
    #pragma unroll
    for (int ni = 0; ni < 4; ++ni) bcol[ni] = bias[col0 + wn * 64 + ni * 16 + l16];
    const int h = (col0 + wn * 64) >> 6;

    if (mtx < 2) {
        const float scale = (mtx == 0) ? (0.125f * LOG2E) : 1.0f;
        unsigned short* hig = (mtx == 0) ? Qhi : Khi;
        #pragma unroll
        for (int mi = 0; mi < 4; ++mi) {
            #pragma unroll
            for (int reg = 0; reg < 4; ++reg) {
                const int r = row0 + wm * 64 + mi * 16 + quad * 4 + reg;
                const int b = r >> 11, n = r & 2047;
                const size_t rowbase = ((size_t)(b * NH + h) * NSEQ + n) * HDIM;
                #pragma unroll
                for (int ni = 0; ni < 4; ++ni) {
                    float f = (acc[mi][ni][reg] + bcol[ni]) * scale;
                    unsigned short hi = f2bf(f);
                    hig[rowbase + ni * 16 + l16] = hi;
                    if (mtx == 0)
                        Qlo[rowbase + ni * 16 + l16] = f2bf(f - bf2f(hi));
                }
            }
        }
    } else {
        // V: bias + bf16, transpose 64x64 per wave through LDS (stride 65)
        unsigned short* vt = (unsigned short*)smem + (size_t)wid * 64 * 65;
        #pragma unroll
        for (int mi = 0; mi < 4; ++mi)
            #pragma unroll
            for (int ni = 0; ni < 4; ++ni)
                #pragma unroll
                for (int reg = 0; reg < 4; ++reg)
                    vt[(mi * 16 + quad * 4 + reg) * 65 + ni * 16 + l16] =
                        f2bf(acc[mi][ni][reg] + bcol[ni]);
        const int b   = row0 >> 11;
        const int n0g = (row0 & 2047) + wm * 64;
        const int bh  = b * NH + h;
        unsigned short* gdst = Vt + ((size_t)bh * HDIM + lane) * NSEQ + n0g;
        #pragma unroll
        for (int nb = 0; nb < 8; ++nb) {
            unsigned short v[8];
            #pragma unroll
            for (int j = 0; j < 8; ++j) v[j] = vt[(nb * 8 + j) * 65 + lane];
            uint4 u;
            u.x = (unsigned)v[0] | ((unsigned)v[1] << 16);
            u.y = (unsigned)v[2] | ((unsigned)v[3] << 16);
            u.z = (unsigned)v[4] | ((unsigned)v[5] << 16);
            u.w = (unsigned)v[6] | ((unsigned)v[7] << 16);
            *(uint4*)(gdst + nb * 8) = u;
        }
    }
}

// ---------------------------------------------------------------------------
// Output projection (MFMA): ctx(hi/lo) @ Wo_hi^T + bo -> out fp32 [B,N,D]
// ---------------------------------------------------------------------------
__global__ __launch_bounds__(256, 2) void out_mfma_kernel(
    const unsigned short* __restrict__ chi, const unsigned short* __restrict__ clo,
    const unsigned short* __restrict__ Wthi,
    const float* __restrict__ bo, float* __restrict__ out)
{
    __shared__ __align__(16) char smem[24576];
    const int t    = threadIdx.x;
    const int lane = t & 63;
    const int wid  = t >> 6;
    const int quad = lane >> 4, l16 = lane & 15;
    const int wm   = wid >> 1,  wn  = wid & 1;

    const int row0 = blockIdx.x * 128;
    const int col0 = blockIdx.y * 128;

    f32x4 acc[4][4];
    #pragma unroll
    for (int i = 0; i < 4; ++i)
        #pragma unroll
        for (int j = 0; j < 4; ++j) acc[i][j] = (f32x4){0.f, 0.f, 0.f, 0.f};

    const size_t wslot = (size_t)3 * DMODEL * DMODEL;   // Wo
    gemm_k_loop(chi + (size_t)row0 * DMODEL, clo + (size_t)row0 * DMODEL,
                Wthi + wslot + (size_t)col0 * DMODEL, smem, acc);

    float bcol[4];
    #pragma unroll
    for (int ni = 0; ni < 4; ++ni) bcol[ni] = bo[col0 + wn * 64 + ni * 16 + l16];
    #pragma unroll
    for (int mi = 0; mi < 4; ++mi)
        #pragma unroll
        for (int reg = 0; reg < 4; ++reg) {
            const int r = row0 + wm * 64 + mi * 16 + quad * 4 + reg;
            float* orow = out + (size_t)r * DMODEL + col0 + wn * 64 + l16;
            #pragma unroll
            for (int ni = 0; ni < 4; ++ni)
                orow[ni * 16] = acc[mi][ni][reg] + bcol[ni];
        }
}

// ---------------------------------------------------------------------------
// MFMA flash attention on 32x32x16: each wave handles 32 q-rows, so every
// K/V/P fragment b128 feeds 2x the MACs of the 16x16 version (LDS-bound fix).
// Block = 4 waves x 32 q = 128 q, 256 threads, 512 blocks (4 blk/CU, 16 w/CU).
// Layouts (guide-measured): C/D col=lane&31, row=(reg&3)+8(reg>>2)+4(lane>>5);
// A/B: [m|n=lane&31][k=(lane>>5)*8+j].
// Mask: 64-bit bitmask AND on P A-frags; l-sum via ones B-frag; p=exp2(s').
// ---------------------------------------------------------------------------
__global__ __launch_bounds__(256) void attn_kernel(
    const unsigned short* __restrict__ Qhi, const unsigned short* __restrict__ Qlo,
    const unsigned short* __restrict__ Khi,
    const unsigned short* __restrict__ Vt,
    const unsigned long long* __restrict__ Mb,
    unsigned short* __restrict__ chi, unsigned short* __restrict__ clo)
{
    __shared__ __align__(16) unsigned short KS[64 * STR];      // 9.2 KB
    __shared__ __align__(16) unsigned short VS[64 * STR];      // 9.2 KB
    __shared__ __align__(16) unsigned short PS[4][32 * STR];   // 18.4 KB

    const int t    = threadIdx.x;
    const int wq   = t >> 6;        // wave 0..3
    const int lane = t & 63;
    const int l32  = lane & 31;
    const int half = lane >> 5;
    const int q0   = blockIdx.x * 128;
    const int h    = blockIdx.y;
    const int b    = blockIdx.z;
    const int bh   = b * NH + h;
    const int qa   = q0 + wq * 32;  // this wave's 32 q-rows

    // Q A-frags: row = qa+l32, k-chunk s*16 + half*8 (scaled 0.125*log2e at proj)
    short8 qh[4], ql[4];
    #pragma unroll
    for (int s = 0; s < 4; ++s) {
        const size_t off = ((size_t)bh * NSEQ + qa + l32) * HDIM + s * 16 + half * 8;
        qh[s] = *(const short8*)(Qhi + off);
        ql[s] = *(const short8*)(Qlo + off);
    }
    const unsigned long long* mrow = Mb + (qa + l32);

    short8 onesf;
    #pragma unroll
    for (int i = 0; i < 8; ++i) onesf[i] = (short)0x3F80;   // bf16 1.0

    f32x16 O0, O1, Ol;
    #pragma unroll
    for (int i = 0; i < 16; ++i) { O0[i] = 0.f; O1[i] = 0.f; Ol[i] = 0.f; }

    const unsigned short* gk = Khi + (size_t)bh * NSEQ * HDIM;
    const unsigned short* gv = Vt  + (size_t)bh * HDIM * NSEQ;
    unsigned short* ps = &PS[wq][0];

    // staging: 512 chunks (64 rows x 8 x 16B) per tile, 2 per thread
    const int ci0 = t, ci1 = t + 256;
    const int sr0 = ci0 >> 3, sc0 = (ci0 & 7) * 8;
    const int sr1 = ci1 >> 3, sc1 = (ci1 & 7) * 8;

    for (int kt = 0; kt < NSEQ / 64; ++kt) {
        const int k0 = kt * 64;
        // ---- stage K [key][hd] and V^T [hd][key] tiles ----
        *(uint4*)&KS[sr0 * STR + sc0] = *(const uint4*)(gk + (size_t)(k0 + sr0) * HDIM + sc0);
        *(uint4*)&KS[sr1 * STR + sc1] = *(const uint4*)(gk + (size_t)(k0 + sr1) * HDIM + sc1);
        *(uint4*)&VS[sr0 * STR + sc0] = *(const uint4*)(gv + (size_t)sr0 * NSEQ + k0 + sc0);
        *(uint4*)&VS[sr1 * STR + sc1] = *(const uint4*)(gv + (size_t)sr1 * NSEQ + k0 + sc1);
        __syncthreads();

        const unsigned long long mw = mrow[(size_t)kt * NSEQ];

        // ---- S' = (Qhi+Qlo) K^T (log2-scaled), per 32-key tile; p=exp2 -> PS ----
        #pragma unroll
        for (int nt = 0; nt < 2; ++nt) {
            f32x16 S;
            #pragma unroll
            for (int i = 0; i < 16; ++i) S[i] = 0.f;
            #pragma unroll
            for (int s = 0; s < 4; ++s) {
                short8 kb = *(const short8*)&KS[(nt * 32 + l32) * STR + s * 16 + half * 8];
                S = MFMA32(qh[s], kb, S, 0, 0, 0);
                S = MFMA32(ql[s], kb, S, 0, 0, 0);
            }
            #pragma unroll
            for (int r = 0; r < 16; ++r) {
                float p = EXP2F(S[r]);
                const int row = (r & 3) + 8 * (r >> 2) + 4 * half;
                ps[row * STR + nt * 32 + l32] =
                    (unsigned short)(__float_as_uint(p) >> 16);
            }
        }

        // ---- P A-frags (row=qa+l32, key chunk s*16+half*8), apply bitmask ----
        short8 pf[4];
        #pragma unroll
        for (int s = 0; s < 4; ++s) {
            pf[s] = *(const short8*)&ps[l32 * STR + s * 16 + half * 8];
            pf[s] = andmask8(pf[s], (unsigned)(mw >> (s * 16 + half * 8)) & 0xFFu);
        }

        // ---- O += P @ V ; l += P @ ones ----
        #pragma unroll
        for (int s = 0; s < 4; ++s) {
            short8 v0 = *(const short8*)&VS[(l32) * STR + s * 16 + half * 8];
            short8 v1 = *(const short8*)&VS[(32 + l32) * STR + s * 16 + half * 8];
            O0 = MFMA32(pf[s], v0, O0, 0, 0, 0);
            O1 = MFMA32(pf[s], v1, O1, 0, 0, 0);
            Ol = MFMA32(pf[s], onesf, Ol, 0, 0, 0);
        }

        __syncthreads();   // protect KS/VS before next staging
    }

    // ---- normalize by l (Ol reg r = row sum for same row) and write ctx ----
    #pragma unroll
    for (int r = 0; r < 16; ++r) {
        const int qrow = qa + (r & 3) + 8 * (r >> 2) + 4 * half;
        const float inv = 1.0f / Ol[r];
        const size_t base = ((size_t)b * NSEQ + qrow) * DMODEL + h * HDIM + l32;
        float f0 = O0[r] * inv;
        float f1 = O1[r] * inv;
        unsigned short h0 = f2bf(f0), h1 = f2bf(f1);
        chi[base]      = h0;
        chi[base + 32] = h1;
        clo[base]      = f2bf(f0 - bf2f(h0));
        clo[base + 32] = f2bf(f1 - bf2f(h1));
    }
}

// ---------------------------------------------------------------------------
extern "C" void kernel_launch(void* const* d_in, const int* in_sizes, int n_in,
                              void* d_out, int out_size, void* d_ws, size_t ws_size,
                              hipStream_t stream) {
    const float* x   = (const float*)d_in[0];
    const float* adj = (const float*)d_in[1];
    const float* Wq  = (const float*)d_in[2];
    const float* bq  = (const float*)d_in[3];
    const float* Wk  = (const float*)d_in[4];
    const float* bk  = (const float*)d_in[5];
    const float* Wv  = (const float*)d_in[6];
    const float* bv  = (const float*)d_in[7];
    const float* Wo  = (const float*)d_in[8];
    const float* bo  = (const float*)d_in[9];
    float* out = (float*)d_out;

    const size_t elems = (size_t)NB * NSEQ * DMODEL;   // 4,194,304
    unsigned short* Qhi  = (unsigned short*)d_ws;
    unsigned short* Qlo  = Qhi + elems;
    unsigned short* Khi  = Qlo + elems;
    unsigned short* Klo  = Khi + elems;                // unused (layout stability)
    unsigned short* Vt   = Klo + elems;
    unsigned long long* Mbits = (unsigned long long*)(Vt + elems);  // 512 KB slot
    unsigned short* xhi  = Vt + 2 * elems;             // after the mask slot
    unsigned short* xlo  = xhi + elems;
    unsigned short* Wthi = xlo + elems;                // 4 * 512*512
    // ctx aliases xhi/xlo (dead after qkv_mfma_kernel)
    unsigned short* chi = xhi;
    unsigned short* clo = xlo;

    mask_kernel   <<<dim3(16384), dim3(256), 0, stream>>>(adj, Mbits);
    split_x_kernel<<<dim3(4096), dim3(256), 0, stream>>>(x, xhi, xlo);
    split_wt_kernel<<<dim3(16, 16, 4), dim3(256), 0, stream>>>(Wq, Wk, Wv, Wo, Wthi);
    qkv_mfma_kernel<<<dim3(64, 12), dim3(256), 0, stream>>>(
        xhi, xlo, Wthi, bq, bk, bv, Qhi, Qlo, Khi, Vt);
    attn_kernel<<<dim3(NSEQ / 128, NH, NB), dim3(256), 0, stream>>>(
        Qhi, Qlo, Khi, Vt, Mbits, chi, clo);
    out_mfma_kernel<<<dim3(64, 4), dim3(256), 0, stream>>>(
        chi, clo, Wthi, bo, out);
}

// Round 12
// 204.002 us; speedup vs baseline: 1.4721x; 1.0832x over previous
//
#include <hip/hip_runtime.h>
#include <math.h>

#define NB    4
#define NSEQ  2048
#define DMODEL 512
#define NH    8
#define HDIM  64
#define STR   72   // attn LDS tile row stride (bf16 units): 144B rows, 16B-aligned
#define LOG2E 1.44269504088896f

typedef __attribute__((ext_vector_type(8))) short short8;
typedef __attribute__((ext_vector_type(4))) float f32x4;
typedef __attribute__((ext_vector_type(16))) float f32x16;
#define MFMA16 __builtin_amdgcn_mfma_f32_16x16x32_bf16
#define MFMA32 __builtin_amdgcn_mfma_f32_32x32x16_bf16
#define EXP2F __builtin_amdgcn_exp2f

__device__ __forceinline__ unsigned short f2bf(float f) {
    union { float f; unsigned int u; } v; v.f = f;
    unsigned int u = v.u;
    unsigned int r = (u + 0x7FFFu + ((u >> 16) & 1u)) >> 16;   // RNE
    return (unsigned short)r;
}
// AND a P-fragment (8 bf16, keys j=0..7) with 8 adjacency bits
__device__ __forceinline__ short8 andmask8(short8 p, unsigned bits) {
    union { short8 s; uint4 u; } x; x.s = p;
    x.u.x &= ((bits &   1u) ? 0xFFFFu : 0u) | ((bits &   2u) ? 0xFFFF0000u : 0u);
    x.u.y &= ((bits &   4u) ? 0xFFFFu : 0u) | ((bits &   8u) ? 0xFFFF0000u : 0u);
    x.u.z &= ((bits &  16u) ? 0xFFFFu : 0u) | ((bits &  32u) ? 0xFFFF0000u : 0u);
    x.u.w &= ((bits &  64u) ? 0xFFFFu : 0u) | ((bits & 128u) ? 0xFFFF0000u : 0u);
    return x.s;
}
__device__ __forceinline__ void async16(void* lds, const void* g) {
    __builtin_amdgcn_global_load_lds(
        (const __attribute__((address_space(1))) unsigned int*)g,
        (__attribute__((address_space(3))) unsigned int*)lds, 16, 0, 0);
}

// ---------------------------------------------------------------------------
// Mask precompute: Mb[kt*2048 + q] = 64-bit word, bit i = adj[q][kt*64+i] > 0.5
// ---------------------------------------------------------------------------
__global__ __launch_bounds__(256) void mask_kernel(const float* __restrict__ adj,
                                                   unsigned long long* __restrict__ Mb) {
    const int w    = blockIdx.x * 4 + (threadIdx.x >> 6);
    const int lane = threadIdx.x & 63;
    const int q  = w >> 5;
    const int kt = w & 31;
    float a = adj[(size_t)q * NSEQ + kt * 64 + lane];
    unsigned long long m = __ballot(a > 0.5f);
    if (lane == 0) Mb[(size_t)kt * NSEQ + q] = m;
}

// ---------------------------------------------------------------------------
// Convert x (fp32) -> bf16
// ---------------------------------------------------------------------------
__global__ __launch_bounds__(256) void split_x_kernel(const float* __restrict__ x,
                                                      unsigned short* __restrict__ xhi) {
    int gid = blockIdx.x * 256 + threadIdx.x;
    float4 a = ((const float4*)x)[gid];
    ushort4 h4;
    h4.x = f2bf(a.x); h4.y = f2bf(a.y); h4.z = f2bf(a.z); h4.w = f2bf(a.w);
    ((ushort4*)xhi)[gid] = h4;
}

// ---------------------------------------------------------------------------
// Transpose weights: W[k][n] fp32 -> Wt [mat][n][k] bf16.
// ---------------------------------------------------------------------------
__global__ __launch_bounds__(256) void split_wt_kernel(
    const float* __restrict__ Wq, const float* __restrict__ Wk,
    const float* __restrict__ Wv, const float* __restrict__ Wo,
    unsigned short* __restrict__ Wthi)
{
    __shared__ float tile[32][33];
    const int m = blockIdx.z;
    const float* W = (m == 0) ? Wq : (m == 1) ? Wk : (m == 2) ? Wv : Wo;
    const int k0 = blockIdx.x * 32, n0 = blockIdx.y * 32;
    const int tx = threadIdx.x & 31, ty = threadIdx.x >> 5;
    #pragma unroll
    for (int i = 0; i < 4; ++i)
        tile[ty * 4 + i][tx] = W[(size_t)(k0 + ty * 4 + i) * DMODEL + n0 + tx];
    __syncthreads();
    const size_t base = ((size_t)m * DMODEL) * DMODEL;
    #pragma unroll
    for (int i = 0; i < 4; ++i) {
        float f = tile[tx][ty * 4 + i];
        size_t idx = base + (size_t)(n0 + ty * 4 + i) * DMODEL + k0 + tx;
        Wthi[idx] = f2bf(f);
    }
}

// ---------------------------------------------------------------------------
// Plain bf16 MFMA GEMM K-loop: 128x128 tile, BK=32, XOR-swizzled LDS,
// global_load_lds staging.
// ---------------------------------------------------------------------------
__device__ __forceinline__ void gemm_k_loop(
    const unsigned short* __restrict__ Ah,
    const unsigned short* __restrict__ Bh,
    char* smem, f32x4 acc[4][4])
{
    const int t    = threadIdx.x;
    const int lane = t & 63;
    const int wid  = t >> 6;
    const int quad = lane >> 4, l16 = lane & 15;
    const int wm   = wid >> 1,  wn  = wid & 1;

    unsigned short* As_h = (unsigned short*)(smem);
    unsigned short* Bs_h = (unsigned short*)(smem + 8192);

    const int ci0 = t, ci1 = 256 + t;
    const int r0 = ci0 >> 2, r1 = ci1 >> 2;
    const int c0 = (ci0 & 3) ^ ((r0 >> 1) & 3);
    const int c1 = (ci1 & 3) ^ ((r1 >> 1) & 3);
    const char* gAh = (const char*)Ah;
    const char* gBh = (const char*)Bh;
    const int ca = quad ^ ((l16 >> 1) & 3);

    for (int k0 = 0; k0 < DMODEL; k0 += 32) {
        const int kb = k0 * 2;
        async16(As_h + ci0 * 8, gAh + r0 * 1024 + kb + c0 * 16);
        async16(As_h + ci1 * 8, gAh + r1 * 1024 + kb + c1 * 16);
        async16(Bs_h + ci0 * 8, gBh + r0 * 1024 + kb + c0 * 16);
        async16(Bs_h + ci1 * 8, gBh + r1 * 1024 + kb + c1 * 16);
        __syncthreads();

        short8 ah[4], bh[4];
        #pragma unroll
        for (int i = 0; i < 4; ++i) {
            const int Ra = wm * 64 + i * 16 + l16;
            ah[i] = *(const short8*)(As_h + Ra * 32 + ca * 8);
            const int Rb = wn * 64 + i * 16 + l16;
            bh[i] = *(const short8*)(Bs_h + Rb * 32 + ca * 8);
        }
        #pragma unroll
        for (int mi = 0; mi < 4; ++mi)
            #pragma unroll
            for (int ni = 0; ni < 4; ++ni)
                acc[mi][ni] = MFMA16(ah[mi], bh[ni], acc[mi][ni], 0, 0, 0);
        __syncthreads();
    }
}

// ---------------------------------------------------------------------------
// QKV projection (MFMA, bf16). Q: *(0.125*log2e); K: plain; V: transposed.
// ---------------------------------------------------------------------------
__global__ __launch_bounds__(256, 2) void qkv_mfma_kernel(
    const unsigned short* __restrict__ xhi,
    const unsigned short* __restrict__ Wthi,
    const float* __restrict__ bq, const float* __restrict__ bk, const float* __restrict__ bv,
    unsigned short* __restrict__ Qhi,
    unsigned short* __restrict__ Khi,
    unsigned short* __restrict__ Vt)
{
    __shared__ __align__(16) char smem[33280];
    const int t    = threadIdx.x;
    const int lane = t & 63;
    const int wid  = t >> 6;
    const int quad = lane >> 4, l16 = lane & 15;
    const int wm   = wid >> 1,  wn  = wid & 1;

    const int row0 = blockIdx.x * 128;
    const int yb   = blockIdx.y;
    const int mtx  = yb >> 2;
    const int col0 = (yb & 3) * 128;

    f32x4 acc[4][4];
    #pragma unroll
    for (int i = 0; i < 4; ++i)
        #pragma unroll
        for (int j = 0; j < 4; ++j) acc[i][j] = (f32x4){0.f, 0.f, 0.f, 0.f};

    const size_t wslot = (size_t)mtx * DMODEL * DMODEL;
    gemm_k_loop(xhi + (size_t)row0 * DMODEL,
                Wthi + wslot + (size_t)col0 * DMODEL, smem, acc);

    const float* bias = (mtx == 0) ? bq : (mtx == 1) ? bk : bv;
    float bcol[4];
    #pragma unroll
    for (int ni = 0; ni < 4; ++ni) bcol[ni] = bias[col0 + wn * 64 + ni * 16 + l16];
    const int h = (col0 + wn * 64) >> 6;

    if (mtx < 2) {
        const float scale = (mtx == 0) ? (0.125f * LOG2E) : 1.0f;
        unsigned short* hig = (mtx == 0) ? Qhi : Khi;
        #pragma unroll
        for (int mi = 0; mi < 4; ++mi) {
            #pragma unroll
            for (int reg = 0; reg < 4; ++reg) {
                const int r = row0 + wm * 64 + mi * 16 + quad * 4 + reg;
                const int b = r >> 11, n = r & 2047;
                const size_t rowbase = ((size_t)(b * NH + h) * NSEQ + n) * HDIM;
                #pragma unroll
                for (int ni = 0; ni < 4; ++ni)
                    hig[rowbase + ni * 16 + l16] =
                        f2bf((acc[mi][ni][reg] + bcol[ni]) * scale);
            }
        }
    } else {
        // V: bias + bf16, transpose 64x64 per wave through LDS (stride 65)
        unsigned short* vt = (unsigned short*)smem + (size_t)wid * 64 * 65;
        #pragma unroll
        for (int mi = 0; mi < 4; ++mi)
            #pragma unroll
            for (int ni = 0; ni < 4; ++ni)
                #pragma unroll
                for (int reg = 0; reg < 4; ++reg)
                    vt[(mi * 16 + quad * 4 + reg) * 65 + ni * 16 + l16] =
                        f2bf(acc[mi][ni][reg] + bcol[ni]);
        const int b   = row0 >> 11;
        const int n0g = (row0 & 2047) + wm * 64;
        const int bh  = b * NH + h;
        unsigned short* gdst = Vt + ((size_t)bh * HDIM + lane) * NSEQ + n0g;
        #pragma unroll
        for (int nb = 0; nb < 8; ++nb) {
            unsigned short v[8];
            #pragma unroll
            for (int j = 0; j < 8; ++j) v[j] = vt[(nb * 8 + j) * 65 + lane];
            uint4 u;
            u.x = (unsigned)v[0] | ((unsigned)v[1] << 16);
            u.y = (unsigned)v[2] | ((unsigned)v[3] << 16);
            u.z = (unsigned)v[4] | ((unsigned)v[5] << 16);
            u.w = (unsigned)v[6] | ((unsigned)v[7] << 16);
            *(uint4*)(gdst + nb * 8) = u;
        }
    }
}

// ---------------------------------------------------------------------------
// Output projection (MFMA): ctx(bf16) @ Wo^T + bo -> out fp32 [B,N,D]
// ---------------------------------------------------------------------------
__global__ __launch_bounds__(256, 2) void out_mfma_kernel(
    const unsigned short* __restrict__ chi,
    const unsigned short* __restrict__ Wthi,
    const float* __restrict__ bo, float* __restrict__ out)
{
    __shared__ __align__(16) char smem[16384];
    const int t    = threadIdx.x;
    const int lane = t & 63;
    const int wid  = t >> 6;
    const int quad = lane >> 4, l16 = lane & 15;
    const int wm   = wid >> 1,  wn  = wid & 1;

    const int row0 = blockIdx.x * 128;
    const int col0 = blockIdx.y * 128;

    f32x4 acc[4][4];
    #pragma unroll
    for (int i = 0; i < 4; ++i)
        #pragma unroll
        for (int j = 0; j < 4; ++j) acc[i][j] = (f32x4){0.f, 0.f, 0.f, 0.f};

    const size_t wslot = (size_t)3 * DMODEL * DMODEL;   // Wo
    gemm_k_loop(chi + (size_t)row0 * DMODEL,
                Wthi + wslot + (size_t)col0 * DMODEL, smem, acc);

    float bcol[4];
    #pragma unroll
    for (int ni = 0; ni < 4; ++ni) bcol[ni] = bo[col0 + wn * 64 + ni * 16 + l16];
    #pragma unroll
    for (int mi = 0; mi < 4; ++mi)
        #pragma unroll
        for (int reg = 0; reg < 4; ++reg) {
            const int r = row0 + wm * 64 + mi * 16 + quad * 4 + reg;
            float* orow = out + (size_t)r * DMODEL + col0 + wn * 64 + l16;
            #pragma unroll
            for (int ni = 0; ni < 4; ++ni)
                orow[ni * 16] = acc[mi][ni][reg] + bcol[ni];
        }
}

// ---------------------------------------------------------------------------
// MFMA flash attention, 32x32x16, 2-way K-SPLIT.
// No-max softmax is additive: O and l are plain sums, so each (q-tile, k-half)
// block writes fp32 partials; merge_kernel combines. Grid 1024 blocks
// (16 qt x 8 h x 8 (b,ks)) -> 4 blk/CU, 16 waves/CU (fixes r11's 8-wave cap).
// Block = 4 waves x 32 q = 128 q, 256 threads. Conflict-free LDS (r11 layout).
// ---------------------------------------------------------------------------
__global__ __launch_bounds__(256) void attn_kernel(
    const unsigned short* __restrict__ Qhi,
    const unsigned short* __restrict__ Khi,
    const unsigned short* __restrict__ Vt,
    const unsigned long long* __restrict__ Mb,
    float* __restrict__ Opart, float* __restrict__ lpart)
{
    __shared__ __align__(16) unsigned short KS[64 * STR];      // 9.2 KB
    __shared__ __align__(16) unsigned short VS[64 * STR];      // 9.2 KB
    __shared__ __align__(16) unsigned short PS[4][32 * STR];   // 18.4 KB

    const int t    = threadIdx.x;
    const int wq   = t >> 6;        // wave 0..3
    const int lane = t & 63;
    const int l32  = lane & 31;
    const int hw   = lane >> 5;     // half-wave
    const int q0   = blockIdx.x * 128;
    const int h    = blockIdx.y;
    const int z    = blockIdx.z;
    const int b    = z >> 1;
    const int ks   = z & 1;         // k-split half
    const int bh   = b * NH + h;
    const int qa   = q0 + wq * 32;

    // Q A-frags: row = qa+l32, k-chunk s*16 + hw*8 (scaled 0.125*log2e at proj)
    short8 qh[4];
    #pragma unroll
    for (int s = 0; s < 4; ++s)
        qh[s] = *(const short8*)(Qhi + ((size_t)bh * NSEQ + qa + l32) * HDIM + s * 16 + hw * 8);
    const unsigned long long* mrow = Mb + (qa + l32);

    short8 onesf;
    #pragma unroll
    for (int i = 0; i < 8; ++i) onesf[i] = (short)0x3F80;   // bf16 1.0

    f32x16 O0, O1, Ol;
    #pragma unroll
    for (int i = 0; i < 16; ++i) { O0[i] = 0.f; O1[i] = 0.f; Ol[i] = 0.f; }

    const unsigned short* gk = Khi + (size_t)bh * NSEQ * HDIM;
    const unsigned short* gv = Vt  + (size_t)bh * HDIM * NSEQ;
    unsigned short* ps = &PS[wq][0];

    const int ci0 = t, ci1 = t + 256;
    const int sr0 = ci0 >> 3, sc0 = (ci0 & 7) * 8;
    const int sr1 = ci1 >> 3, sc1 = (ci1 & 7) * 8;

    for (int kt = ks * 16; kt < ks * 16 + 16; ++kt) {
        const int k0 = kt * 64;
        // ---- stage K [key][hd] and V^T [hd][key] tiles ----
        *(uint4*)&KS[sr0 * STR + sc0] = *(const uint4*)(gk + (size_t)(k0 + sr0) * HDIM + sc0);
        *(uint4*)&KS[sr1 * STR + sc1] = *(const uint4*)(gk + (size_t)(k0 + sr1) * HDIM + sc1);
        *(uint4*)&VS[sr0 * STR + sc0] = *(const uint4*)(gv + (size_t)sr0 * NSEQ + k0 + sc0);
        *(uint4*)&VS[sr1 * STR + sc1] = *(const uint4*)(gv + (size_t)sr1 * NSEQ + k0 + sc1);
        __syncthreads();

        const unsigned long long mw = mrow[(size_t)kt * NSEQ];

        // ---- S' = Q K^T (log2-scaled), per 32-key tile; p=exp2 -> PS ----
        #pragma unroll
        for (int nt = 0; nt < 2; ++nt) {
            f32x16 S;
            #pragma unroll
            for (int i = 0; i < 16; ++i) S[i] = 0.f;
            #pragma unroll
            for (int s = 0; s < 4; ++s) {
                short8 kb = *(const short8*)&KS[(nt * 32 + l32) * STR + s * 16 + hw * 8];
                S = MFMA32(qh[s], kb, S, 0, 0, 0);
            }
            #pragma unroll
            for (int r = 0; r < 16; ++r) {
                float p = EXP2F(S[r]);
                const int row = (r & 3) + 8 * (r >> 2) + 4 * hw;
                ps[row * STR + nt * 32 + l32] =
                    (unsigned short)(__float_as_uint(p) >> 16);
            }
        }

        // ---- P A-frags, apply bitmask ----
        short8 pf[4];
        #pragma unroll
        for (int s = 0; s < 4; ++s) {
            pf[s] = *(const short8*)&ps[l32 * STR + s * 16 + hw * 8];
            pf[s] = andmask8(pf[s], (unsigned)(mw >> (s * 16 + hw * 8)) & 0xFFu);
        }

        // ---- O += P @ V ; l += P @ ones ----
        #pragma unroll
        for (int s = 0; s < 4; ++s) {
            short8 v0 = *(const short8*)&VS[(l32) * STR + s * 16 + hw * 8];
            short8 v1 = *(const short8*)&VS[(32 + l32) * STR + s * 16 + hw * 8];
            O0 = MFMA32(pf[s], v0, O0, 0, 0, 0);
            O1 = MFMA32(pf[s], v1, O1, 0, 0, 0);
            Ol = MFMA32(pf[s], onesf, Ol, 0, 0, 0);
        }

        __syncthreads();   // protect KS/VS before next staging
    }

    // ---- write fp32 partials (no normalization; merge kernel sums) ----
    const size_t obase = ((size_t)(ks * NB + b) * NH + h) * NSEQ;
    #pragma unroll
    for (int r = 0; r < 16; ++r) {
        const int qrow = qa + (r & 3) + 8 * (r >> 2) + 4 * hw;
        float* orow = Opart + (obase + qrow) * HDIM;
        orow[l32]      = O0[r];
        orow[32 + l32] = O1[r];
        if (l32 == 0) lpart[obase + qrow] = Ol[r];
    }
}

// ---------------------------------------------------------------------------
// Merge: ctx = (O_half0 + O_half1) / (l0 + l1), bf16 -> chi [B,N,D]
// ---------------------------------------------------------------------------
__global__ __launch_bounds__(256) void merge_kernel(
    const float* __restrict__ Opart, const float* __restrict__ lpart,
    unsigned short* __restrict__ chi)
{
    const int g = blockIdx.x * 256 + threadIdx.x;   // 262144 threads
    const int qitem = g >> 2;                       // (b*NH+h)*NSEQ+n
    const int grp = g & 3;                          // 16-dim group
    const size_t HS = (size_t)NB * NH * NSEQ * HDIM;
    const float* pa = Opart + (size_t)qitem * HDIM + grp * 16;
    const float* pb = pa + HS;
    const float inv = 1.0f / (lpart[qitem] + lpart[qitem + NB * NH * NSEQ]);

    const int n = qitem & 2047, h = (qitem >> 11) & 7, b = qitem >> 14;
    unsigned short* dst = chi + ((size_t)b * NSEQ + n) * DMODEL + h * HDIM + grp * 16;

    unsigned short o[16];
    #pragma unroll
    for (int i = 0; i < 16; i += 4) {
        float4 a4 = *(const float4*)(pa + i);
        float4 b4 = *(const float4*)(pb + i);
        o[i + 0] = f2bf((a4.x + b4.x) * inv);
        o[i + 1] = f2bf((a4.y + b4.y) * inv);
        o[i + 2] = f2bf((a4.z + b4.z) * inv);
        o[i + 3] = f2bf((a4.w + b4.w) * inv);
    }
    uint4 u0, u1;
    u0.x = (unsigned)o[0]  | ((unsigned)o[1]  << 16);
    u0.y = (unsigned)o[2]  | ((unsigned)o[3]  << 16);
    u0.z = (unsigned)o[4]  | ((unsigned)o[5]  << 16);
    u0.w = (unsigned)o[6]  | ((unsigned)o[7]  << 16);
    u1.x = (unsigned)o[8]  | ((unsigned)o[9]  << 16);
    u1.y = (unsigned)o[10] | ((unsigned)o[11] << 16);
    u1.z = (unsigned)o[12] | ((unsigned)o[13] << 16);
    u1.w = (unsigned)o[14] | ((unsigned)o[15] << 16);
    *(uint4*)dst = u0;
    *(uint4*)(dst + 8) = u1;
}

// ---------------------------------------------------------------------------
extern "C" void kernel_launch(void* const* d_in, const int* in_sizes, int n_in,
                              void* d_out, int out_size, void* d_ws, size_t ws_size,
                              hipStream_t stream) {
    const float* x   = (const float*)d_in[0];
    const float* adj = (const float*)d_in[1];
    const float* Wq  = (const float*)d_in[2];
    const float* bq  = (const float*)d_in[3];
    const float* Wk  = (const float*)d_in[4];
    const float* bk  = (const float*)d_in[5];
    const float* Wv  = (const float*)d_in[6];
    const float* bv  = (const float*)d_in[7];
    const float* Wo  = (const float*)d_in[8];
    const float* bo  = (const float*)d_in[9];
    float* out = (float*)d_out;

    const size_t elems = (size_t)NB * NSEQ * DMODEL;   // 4,194,304
    unsigned short* Qhi  = (unsigned short*)d_ws;                    // 8.4 MB
    unsigned short* Khi  = Qhi + elems;                              // 8.4 MB
    unsigned short* Vt   = Khi + elems;                              // 8.4 MB
    unsigned long long* Mbits = (unsigned long long*)(Vt + elems);   // 512 KB
    unsigned short* xhi  = (unsigned short*)(Mbits + 32 * NSEQ);     // 8.4 MB
    unsigned short* Wthi = xhi + elems;                              // 2 MB
    float* Opart = (float*)(Wthi + 4 * (size_t)DMODEL * DMODEL);     // 33.5 MB
    float* lpart = Opart + 2 * (size_t)NB * NH * NSEQ * HDIM;        // 512 KB
    // ctx (bf16) aliases xhi (dead after qkv_mfma_kernel)
    unsigned short* chi = xhi;

    mask_kernel   <<<dim3(16384), dim3(256), 0, stream>>>(adj, Mbits);
    split_x_kernel<<<dim3(4096), dim3(256), 0, stream>>>(x, xhi);
    split_wt_kernel<<<dim3(16, 16, 4), dim3(256), 0, stream>>>(Wq, Wk, Wv, Wo, Wthi);
    qkv_mfma_kernel<<<dim3(64, 12), dim3(256), 0, stream>>>(
        xhi, Wthi, bq, bk, bv, Qhi, Khi, Vt);
    attn_kernel<<<dim3(NSEQ / 128, NH, NB * 2), dim3(256), 0, stream>>>(
        Qhi, Khi, Vt, Mbits, Opart, lpart);
    merge_kernel<<<dim3(1024), dim3(256), 0, stream>>>(Opart, lpart, chi);
    out_mfma_kernel<<<dim3(64, 4), dim3(256), 0, stream>>>(
        chi, Wthi, bo, out);
}